// Round 11
// baseline (108.220 us; speedup 1.0000x reference)
//
#include <hip/hip_runtime.h>

#define B 4
#define D 128
#define K 512
#define TI 8

typedef __fp16 h2v __attribute__((ext_vector_type(2)));

__device__ __forceinline__ unsigned pkrtz(float a, float b) {
  h2v h = __builtin_amdgcn_cvt_pkrtz(a, b);
  union { h2v h; unsigned u; } c; c.h = h; return c.u;
}
__device__ __forceinline__ h2v u2h(unsigned u) {
  union { unsigned u; h2v h; } c; c.u = u; return c.h;
}
__device__ __forceinline__ float fdot2f(h2v a, h2v b, float c) {
#if __has_builtin(__builtin_amdgcn_fdot2)
  return __builtin_amdgcn_fdot2(a, b, c, false);
#else
  return c + (float)a.x * (float)b.x + (float)a.y * (float)b.y;
#endif
}
__device__ __forceinline__ h2v relu2(h2v a) {
#if __has_builtin(__builtin_elementwise_max)
  const h2v z = {(__fp16)0.f, (__fp16)0.f};
  return __builtin_elementwise_max(a, z);  // v_pk_max_f16
#else
  h2v r;
  r.x = (float)a.x > 0.f ? a.x : (__fp16)0.f;
  r.y = (float)a.y > 0.f ? a.y : (__fp16)0.f;
  return r;
#endif
}

// ---------------- K1: Lhat^T, Rhat^T (f16 e-pairs) + XhT (f16 j-pairs) -----
// Grid (K/64, D/16, B) = 256 blocks x 256 thr.  (unchanged from r8/r10)
__global__ __launch_bounds__(256) void gat_lr16(
    const float* __restrict__ x, const float* __restrict__ lin_w,
    const float* __restrict__ lin_b, const float* __restrict__ a,
    unsigned* __restrict__ LhT, unsigned* __restrict__ RhT,
    unsigned* __restrict__ XhT) {
  const int j0 = blockIdx.x * 64;
  const int E0 = blockIdx.y * 16;
  const int b = blockIdx.z;
  const int t = threadIdx.x;
  __shared__ float sx[D][64];    // 32 KB x-tile
  __shared__ float sw1[D][16];   // 8 KB W1 slab
  __shared__ float sw2[D][16];   // 8 KB W2 slab
#pragma unroll
  for (int r = 0; r < 8; ++r) {  // x-tile: 2048 float4s
    const int fid = t + 256 * r;
    const int row = fid >> 4, c4 = fid & 15;
    *(float4*)&sx[row][4 * c4] =
        *(const float4*)&x[((size_t)b * D + row) * K + j0 + 4 * c4];
  }
#pragma unroll
  for (int r = 0; r < 8; ++r) {  // W slabs
    const int idx = t + 256 * r;
    const int row = idx >> 4, e = idx & 15;
    sw1[row][e] = lin_w[(size_t)row * D + E0 + e];
    sw2[row][e] = lin_w[(size_t)(D + row) * D + E0 + e];
  }
  __syncthreads();
  // this E0-slice emits its 2/16 share of the f16-packed x for this j-tile
  {
    const int ry = blockIdx.y * 2;
#pragma unroll
    for (int r = ry; r < ry + 2; ++r) {
      const int idx = t + 256 * r;       // 0..4095
      const int row = idx >> 5, jc = idx & 31;
      XhT[((size_t)b * D + row) * (K / 2) + (j0 >> 1) + jc] =
          pkrtz(sx[row][2 * jc], sx[row][2 * jc + 1]);
    }
  }
  const int j = t & 63, g = t >> 6;  // wave g owns e-quad E0+4g..+3
  float accL[4] = {0.f, 0.f, 0.f, 0.f}, accR[4] = {0.f, 0.f, 0.f, 0.f};
#pragma unroll 8
  for (int c = 0; c < D; ++c) {
    const float xv = sx[c][j];
    const float4 w1 = *(const float4*)&sw1[c][4 * g];  // wave-uniform: bcast
    const float4 w2 = *(const float4*)&sw2[c][4 * g];
    accL[0] = fmaf(xv, w1.x, accL[0]);
    accL[1] = fmaf(xv, w1.y, accL[1]);
    accL[2] = fmaf(xv, w1.z, accL[2]);
    accL[3] = fmaf(xv, w1.w, accL[3]);
    accR[0] = fmaf(xv, w2.x, accR[0]);
    accR[1] = fmaf(xv, w2.y, accR[1]);
    accR[2] = fmaf(xv, w2.z, accR[2]);
    accR[3] = fmaf(xv, w2.w, accR[3]);
  }
  const int e0 = E0 + 4 * g;
#pragma unroll
  for (int u = 0; u < 2; ++u) {
    const int ea = e0 + 2 * u, eb = ea + 1;
    const float uea = 0.8f * fabsf(a[ea]), ueb = 0.8f * fabsf(a[eb]);
    const float La = uea * (accL[2 * u] + lin_b[ea]);
    const float Lb = ueb * (accL[2 * u + 1] + lin_b[eb]);
    const float Ra = uea * accR[2 * u];
    const float Rb = ueb * accR[2 * u + 1];
    const size_t dp = (size_t)(ea >> 1);
    LhT[((size_t)b * (D / 2) + dp) * K + j0 + j] = pkrtz(La, Lb);
    RhT[((size_t)b * (D / 2) + dp) * K + j0 + j] = pkrtz(Ra, Rb);
  }
}

// ---------------- K2: TI=8, 512 thr, 2 blocks/CU; lh via scalar loads -----
__global__ __launch_bounds__(512, 4) void gat_attn16(
    const float* __restrict__ x, const float* __restrict__ a,
    const float* __restrict__ bias, const unsigned* __restrict__ LhT,
    const unsigned* __restrict__ RhT, const unsigned* __restrict__ XhT,
    float* __restrict__ out) {
  const int i0 = blockIdx.x * TI;
  const int b = blockIdx.y;
  const int t = threadIdx.x;
  __shared__ unsigned ssg[D / 2];         // sign(a) f16 pairs
  __shared__ float sSL[TI];
  __shared__ float seT[TI][K];            // raw scores, 16 KB
  __shared__ unsigned sattn16[TI][K / 2]; // attn f16 j-pairs, 8 KB

  // ---- A: signs ----
  if (t < D / 2) {
    const float s0 = (a[2 * t] >= 0.f) ? 1.f : -1.f;
    const float s1 = (a[2 * t + 1] >= 0.f) ? 1.f : -1.f;
    ssg[t] = pkrtz(s0, s1);
  }
  __syncthreads();
  // ---- B: SLh_i; wave w reduces row ii=w (one-shot global read) ----
  {
    const int ii = t >> 6, dp = t & 63;
    const unsigned lh = LhT[((size_t)b * (D / 2) + dp) * K + i0 + ii];
    float v = fdot2f(u2h(ssg[dp]), u2h(lh), 0.f);
#pragma unroll
    for (int off = 32; off > 0; off >>= 1) v += __shfl_xor(v, off, 64);
    if ((t & 63) == 0) sSL[ii] = v;
  }
  __syncthreads();

  // ---- C: scores; thread = j = t; lh rows are thread-uniform -> SMEM ----
  {
    const unsigned* rc = RhT + (size_t)b * (D / 2) * K + t;
    const unsigned* lrow = LhT + (size_t)b * (D / 2) * K + i0;  // uniform base
    float acc[8] = {0.f, 0.f, 0.f, 0.f, 0.f, 0.f, 0.f, 0.f};
    float sr = 0.f;
#pragma unroll 8
    for (int dp = 0; dp < D / 2; ++dp) {
      const unsigned rr = rc[(size_t)dp * K];
      const uint4 lh4a = *(const uint4*)&lrow[(size_t)dp * K];      // s_load
      const uint4 lh4b = *(const uint4*)&lrow[(size_t)dp * K + 4];  // s_load
      const h2v s2 = u2h(ssg[dp]);
      const h2v rv = u2h(rr);
      sr = fdot2f(s2, rv, sr);
      acc[0] = fdot2f(s2, relu2(u2h(lh4a.x) + rv), acc[0]);
      acc[1] = fdot2f(s2, relu2(u2h(lh4a.y) + rv), acc[1]);
      acc[2] = fdot2f(s2, relu2(u2h(lh4a.z) + rv), acc[2]);
      acc[3] = fdot2f(s2, relu2(u2h(lh4a.w) + rv), acc[3]);
      acc[4] = fdot2f(s2, relu2(u2h(lh4b.x) + rv), acc[4]);
      acc[5] = fdot2f(s2, relu2(u2h(lh4b.y) + rv), acc[5]);
      acc[6] = fdot2f(s2, relu2(u2h(lh4b.z) + rv), acc[6]);
      acc[7] = fdot2f(s2, relu2(u2h(lh4b.w) + rv), acc[7]);
    }
#pragma unroll
    for (int ii = 0; ii < TI; ++ii)
      seT[ii][t] = acc[ii] + 0.25f * (sSL[ii] + sr) +
                   bias[(size_t)(i0 + ii) * K + t];
  }
  __syncthreads();

  // ---- D: softmax; wave w owns row w (8 waves); pack to f16 ----
  {
    const int w = t >> 6, lane = t & 63;
    float2 v[4];
    float m = -1e30f;
#pragma unroll
    for (int q = 0; q < 4; ++q) {
      v[q] = *(const float2*)&seT[w][2 * lane + 128 * q];
      m = fmaxf(m, fmaxf(v[q].x, v[q].y));
    }
#pragma unroll
    for (int off = 32; off > 0; off >>= 1) m = fmaxf(m, __shfl_xor(m, off, 64));
    float s = 0.f;
#pragma unroll
    for (int q = 0; q < 4; ++q) {
      v[q].x = __expf(v[q].x - m);
      v[q].y = __expf(v[q].y - m);
      s += v[q].x + v[q].y;
    }
#pragma unroll
    for (int off = 32; off > 0; off >>= 1) s += __shfl_xor(s, off, 64);
    const float inv = 1.f / s;
#pragma unroll
    for (int q = 0; q < 4; ++q)
      sattn16[w][lane + 64 * q] = pkrtz(v[q].x * inv, v[q].y * inv);
  }
  __syncthreads();

  // ---- E: agg; thread = (dg = t>>4 owns 4 d-rows, jr = t&15 owns 32 j's).
  // Two passes over j-chunks keep attn regs at 64 VGPR (fits 128-cap).
  {
    const int jr = t & 15, dg = t >> 4;
    const unsigned* xh = XhT + (size_t)b * D * (K / 2);
    float accT[4][8];
#pragma unroll
    for (int r = 0; r < 4; ++r)
#pragma unroll
      for (int i = 0; i < 8; ++i) accT[r][i] = 0.f;
#pragma unroll
    for (int p = 0; p < 2; ++p) {
      uint4 ar[8][2];
#pragma unroll
      for (int i = 0; i < 8; ++i)
#pragma unroll
        for (int qq = 0; qq < 2; ++qq)
          ar[i][qq] = *(const uint4*)&sattn16[i][4 * (jr + 16 * (2 * p + qq))];
#pragma unroll
      for (int r = 0; r < 4; ++r) {
        const int d = dg * 4 + r;
#pragma unroll
        for (int qq = 0; qq < 2; ++qq) {
          const uint4 xp =
              *(const uint4*)&xh[(size_t)d * (K / 2) +
                                 4 * (jr + 16 * (2 * p + qq))];
#pragma unroll
          for (int i = 0; i < 8; ++i) {
            accT[r][i] = fdot2f(u2h(ar[i][qq].x), u2h(xp.x), accT[r][i]);
            accT[r][i] = fdot2f(u2h(ar[i][qq].y), u2h(xp.y), accT[r][i]);
            accT[r][i] = fdot2f(u2h(ar[i][qq].z), u2h(xp.z), accT[r][i]);
            accT[r][i] = fdot2f(u2h(ar[i][qq].w), u2h(xp.w), accT[r][i]);
          }
        }
      }
    }
#pragma unroll
    for (int r = 0; r < 4; ++r) {
#pragma unroll
      for (int i = 0; i < 8; ++i) {
        accT[r][i] += __shfl_xor(accT[r][i], 1, 64);
        accT[r][i] += __shfl_xor(accT[r][i], 2, 64);
        accT[r][i] += __shfl_xor(accT[r][i], 4, 64);
        accT[r][i] += __shfl_xor(accT[r][i], 8, 64);
      }
      if (jr == 0) {
        const int d = dg * 4 + r;
        const float* xrow = x + ((size_t)b * D + d) * K + i0;
        const float4 xv0 = *(const float4*)&xrow[0];
        const float4 xv1 = *(const float4*)&xrow[4];
        const float xr[8] = {xv0.x, xv0.y, xv0.z, xv0.w,
                             xv1.x, xv1.y, xv1.z, xv1.w};
        float* orow = out + ((size_t)b * D + d) * K + i0;
#pragma unroll
        for (int i = 0; i < 8; ++i) {
          const float sg = 1.f / (1.f + __expf(-accT[r][i]));
          orow[i] = sg + xr[i];
        }
      }
    }
  }
}

// ---------------- Fallback (ws too small): fused, ws-free ----------------
#define ALPHA 0.2f
__global__ __launch_bounds__(512) void gat_fused(
    const float* __restrict__ x, const float* __restrict__ lin_w,
    const float* __restrict__ lin_b, const float* __restrict__ a,
    const float* __restrict__ bias, float* __restrict__ out) {
  const int i = blockIdx.x, b = blockIdx.y, t = threadIdx.x;
  __shared__ float sxi[D], sLi[D], sa[D];
  __shared__ float lpart[4 * D];
  __shared__ float xtT[D * 64];
  __shared__ float epars[8 * 64];
  __shared__ float se[K];
  __shared__ float sattn[K], spart[K];
  __shared__ float sred[8];

  if (t < D) {
    sxi[t] = x[((size_t)b * D + t) * K + i];
    sa[t] = a[t];
  }
  __syncthreads();
  {
    const int c = t & (D - 1), q = t >> 7;
    float acc = 0.f;
    const float* W1 = lin_w + c;
#pragma unroll 8
    for (int d = q * 32; d < q * 32 + 32; ++d)
      acc = fmaf(sxi[d], W1[(size_t)d * D], acc);
    lpart[q * D + c] = acc;
  }
  __syncthreads();
  if (t < D)
    sLi[t] = lin_b[t] + lpart[t] + lpart[D + t] + lpart[2 * D + t] +
             lpart[3 * D + t];
  __syncthreads();

  for (int jt = 0; jt < K / 64; ++jt) {
    const int j0 = jt * 64;
    for (int idx = t; idx < D * 64; idx += 512)
      xtT[idx] = x[((size_t)b * D + (idx >> 6)) * K + j0 + (idx & 63)];
    __syncthreads();
    const int jj = t & 63, g = t >> 6, dp0 = g * 16;
    float accv[16];
#pragma unroll
    for (int v = 0; v < 16; ++v) accv[v] = 0.f;
    for (int dc = 0; dc < D; dc += 16) {
      float xv[16];
#pragma unroll
      for (int u = 0; u < 16; ++u) xv[u] = xtT[(dc + u) * 64 + jj];
#pragma unroll
      for (int u = 0; u < 16; ++u) {
        const float* W2r = lin_w + (size_t)(D + dc + u) * D + dp0;
#pragma unroll
        for (int v = 0; v < 16; ++v) accv[v] = fmaf(xv[u], W2r[v], accv[v]);
      }
    }
    float ep = 0.f;
#pragma unroll
    for (int v = 0; v < 16; ++v) {
      const float pre = sLi[dp0 + v] + accv[v];
      ep = fmaf(sa[dp0 + v], pre > 0.f ? pre : ALPHA * pre, ep);
    }
    epars[g * 64 + jj] = ep;
    __syncthreads();
    if (t < 64) {
      float esum = bias[(size_t)i * K + j0 + t];
#pragma unroll
      for (int g2 = 0; g2 < 8; ++g2) esum += epars[g2 * 64 + t];
      se[j0 + t] = esum;
    }
    __syncthreads();
  }

  float e = se[t];
  float m = e;
#pragma unroll
  for (int off = 32; off > 0; off >>= 1) m = fmaxf(m, __shfl_xor(m, off, 64));
  if ((t & 63) == 0) sred[t >> 6] = m;
  __syncthreads();
  m = sred[0];
#pragma unroll
  for (int w = 1; w < 8; ++w) m = fmaxf(m, sred[w]);
  const float ev = __expf(e - m);
  float s = ev;
#pragma unroll
  for (int off = 32; off > 0; off >>= 1) s += __shfl_xor(s, off, 64);
  __syncthreads();
  if ((t & 63) == 0) sred[t >> 6] = s;
  __syncthreads();
  s = 0.f;
#pragma unroll
  for (int w = 0; w < 8; ++w) s += sred[w];
  sattn[t] = ev * (1.f / s);
  __syncthreads();

  const int d = t >> 2, c = t & 3;
  const float4* X4 = (const float4*)(x + ((size_t)b * D + d) * K);
  const float4* A4 = (const float4*)sattn;
  float p = 0.f;
#pragma unroll 4
  for (int q = 0; q < K / 16; ++q) {
    const int idx = c + 4 * q;
    float4 xv = X4[idx], av = A4[idx];
    p = fmaf(av.x, xv.x, p);
    p = fmaf(av.y, xv.y, p);
    p = fmaf(av.z, xv.z, p);
    p = fmaf(av.w, xv.w, p);
  }
  spart[t] = p;
  __syncthreads();
  if (t < D) {
    const float agg =
        spart[4 * t] + spart[4 * t + 1] + spart[4 * t + 2] + spart[4 * t + 3];
    const float sg = 1.f / (1.f + __expf(-agg));
    out[((size_t)b * D + t) * K + i] = sg + sxi[t];
  }
}

extern "C" void kernel_launch(void* const* d_in, const int* in_sizes, int n_in,
                              void* d_out, int out_size, void* d_ws,
                              size_t ws_size, hipStream_t stream) {
  const float* x = (const float*)d_in[0];
  const float* lin_w = (const float*)d_in[1];
  const float* lin_b = (const float*)d_in[2];
  const float* a = (const float*)d_in[3];
  const float* bias = (const float*)d_in[4];
  float* out = (float*)d_out;

  const size_t half_words = (size_t)B * (D / 2) * K;  // 512 KB each (L,R)
  const size_t xh_words = (size_t)B * D * (K / 2);    // 512 KB
  const size_t need = (2 * half_words + xh_words) * sizeof(unsigned);
  if (ws_size >= need && d_ws != nullptr) {
    unsigned* LhT = (unsigned*)d_ws;
    unsigned* RhT = LhT + half_words;
    unsigned* XhT = RhT + half_words;
    gat_lr16<<<dim3(K / 64, D / 16, B), 256, 0, stream>>>(x, lin_w, lin_b, a,
                                                          LhT, RhT, XhT);
    gat_attn16<<<dim3(K / TI, B), 512, 0, stream>>>(x, a, bias, LhT, RhT, XhT,
                                                    out);
  } else {
    gat_fused<<<dim3(K, B), 512, 0, stream>>>(x, lin_w, lin_b, a, bias, out);
  }
}

// Round 12
// 84.908 us; speedup vs baseline: 1.2746x; 1.2746x over previous
//
#include <hip/hip_runtime.h>

#define B 4
#define D 128
#define K 512
#define TI 8

typedef __fp16 h2v __attribute__((ext_vector_type(2)));

__device__ __forceinline__ unsigned pkrtz(float a, float b) {
  h2v h = __builtin_amdgcn_cvt_pkrtz(a, b);
  union { h2v h; unsigned u; } c; c.h = h; return c.u;
}
__device__ __forceinline__ h2v u2h(unsigned u) {
  union { unsigned u; h2v h; } c; c.u = u; return c.h;
}
__device__ __forceinline__ float fdot2f(h2v a, h2v b, float c) {
#if __has_builtin(__builtin_amdgcn_fdot2)
  return __builtin_amdgcn_fdot2(a, b, c, false);
#else
  return c + (float)a.x * (float)b.x + (float)a.y * (float)b.y;
#endif
}
__device__ __forceinline__ h2v relu2(h2v a) {
#if __has_builtin(__builtin_elementwise_max)
  const h2v z = {(__fp16)0.f, (__fp16)0.f};
  return __builtin_elementwise_max(a, z);  // v_pk_max_f16
#else
  h2v r;
  r.x = (float)a.x > 0.f ? a.x : (__fp16)0.f;
  r.y = (float)a.y > 0.f ? a.y : (__fp16)0.f;
  return r;
#endif
}

// ---------------- K1: Lhat^T, Rhat^T (f16 e-pairs) + XhT (f16 j-pairs) -----
// Grid (K/64, D/16, B) = 256 blocks x 256 thr.  (unchanged)
__global__ __launch_bounds__(256) void gat_lr16(
    const float* __restrict__ x, const float* __restrict__ lin_w,
    const float* __restrict__ lin_b, const float* __restrict__ a,
    unsigned* __restrict__ LhT, unsigned* __restrict__ RhT,
    unsigned* __restrict__ XhT) {
  const int j0 = blockIdx.x * 64;
  const int E0 = blockIdx.y * 16;
  const int b = blockIdx.z;
  const int t = threadIdx.x;
  __shared__ float sx[D][64];    // 32 KB x-tile
  __shared__ float sw1[D][16];   // 8 KB W1 slab
  __shared__ float sw2[D][16];   // 8 KB W2 slab
#pragma unroll
  for (int r = 0; r < 8; ++r) {  // x-tile: 2048 float4s
    const int fid = t + 256 * r;
    const int row = fid >> 4, c4 = fid & 15;
    *(float4*)&sx[row][4 * c4] =
        *(const float4*)&x[((size_t)b * D + row) * K + j0 + 4 * c4];
  }
#pragma unroll
  for (int r = 0; r < 8; ++r) {  // W slabs
    const int idx = t + 256 * r;
    const int row = idx >> 4, e = idx & 15;
    sw1[row][e] = lin_w[(size_t)row * D + E0 + e];
    sw2[row][e] = lin_w[(size_t)(D + row) * D + E0 + e];
  }
  __syncthreads();
  // this E0-slice emits its 2/16 share of the f16-packed x for this j-tile
  {
    const int ry = blockIdx.y * 2;
#pragma unroll
    for (int r = ry; r < ry + 2; ++r) {
      const int idx = t + 256 * r;       // 0..4095
      const int row = idx >> 5, jc = idx & 31;
      XhT[((size_t)b * D + row) * (K / 2) + (j0 >> 1) + jc] =
          pkrtz(sx[row][2 * jc], sx[row][2 * jc + 1]);
    }
  }
  const int j = t & 63, g = t >> 6;  // wave g owns e-quad E0+4g..+3
  float accL[4] = {0.f, 0.f, 0.f, 0.f}, accR[4] = {0.f, 0.f, 0.f, 0.f};
#pragma unroll 8
  for (int c = 0; c < D; ++c) {
    const float xv = sx[c][j];
    const float4 w1 = *(const float4*)&sw1[c][4 * g];  // wave-uniform: bcast
    const float4 w2 = *(const float4*)&sw2[c][4 * g];
    accL[0] = fmaf(xv, w1.x, accL[0]);
    accL[1] = fmaf(xv, w1.y, accL[1]);
    accL[2] = fmaf(xv, w1.z, accL[2]);
    accL[3] = fmaf(xv, w1.w, accL[3]);
    accR[0] = fmaf(xv, w2.x, accR[0]);
    accR[1] = fmaf(xv, w2.y, accR[1]);
    accR[2] = fmaf(xv, w2.z, accR[2]);
    accR[3] = fmaf(xv, w2.w, accR[3]);
  }
  const int e0 = E0 + 4 * g;
#pragma unroll
  for (int u = 0; u < 2; ++u) {
    const int ea = e0 + 2 * u, eb = ea + 1;
    const float uea = 0.8f * fabsf(a[ea]), ueb = 0.8f * fabsf(a[eb]);
    const float La = uea * (accL[2 * u] + lin_b[ea]);
    const float Lb = ueb * (accL[2 * u + 1] + lin_b[eb]);
    const float Ra = uea * accR[2 * u];
    const float Rb = ueb * accR[2 * u + 1];
    const size_t dp = (size_t)(ea >> 1);
    LhT[((size_t)b * (D / 2) + dp) * K + j0 + j] = pkrtz(La, Lb);
    RhT[((size_t)b * (D / 2) + dp) * K + j0 + j] = pkrtz(Ra, Rb);
  }
}

// ---------------- K2: TI=8, 512 thr; NO min-waves bound (r11 spilled at 64
// VGPR under (512,4)).  Two-pass E keeps VGPR ~<=128 so runtime occupancy can
// reach 2 blocks/CU on its own.
__global__ __launch_bounds__(512) void gat_attn16(
    const float* __restrict__ x, const float* __restrict__ a,
    const float* __restrict__ bias, const unsigned* __restrict__ LhT,
    const unsigned* __restrict__ RhT, const unsigned* __restrict__ XhT,
    float* __restrict__ out) {
  const int i0 = blockIdx.x * TI;
  const int b = blockIdx.y;
  const int t = threadIdx.x;
  __shared__ unsigned ssg[D / 2];         // sign(a) f16 pairs
  __shared__ float sSL[TI];
  __shared__ float seT[TI][K];            // raw scores, 16 KB
  __shared__ unsigned sattn16[TI][K / 2]; // attn f16 j-pairs, 8 KB

  // ---- A: signs ----
  if (t < D / 2) {
    const float s0 = (a[2 * t] >= 0.f) ? 1.f : -1.f;
    const float s1 = (a[2 * t + 1] >= 0.f) ? 1.f : -1.f;
    ssg[t] = pkrtz(s0, s1);
  }
  __syncthreads();
  // ---- B: SLh_i; wave w reduces row ii=w (one-shot global read) ----
  {
    const int ii = t >> 6, dp = t & 63;
    const unsigned lh = LhT[((size_t)b * (D / 2) + dp) * K + i0 + ii];
    float v = fdot2f(u2h(ssg[dp]), u2h(lh), 0.f);
#pragma unroll
    for (int off = 32; off > 0; off >>= 1) v += __shfl_xor(v, off, 64);
    if ((t & 63) == 0) sSL[ii] = v;
  }
  __syncthreads();

  // ---- C: scores; thread = j = t; lh rows are thread-uniform -> s_load ----
  {
    const unsigned* rc = RhT + (size_t)b * (D / 2) * K + t;
    const unsigned* lrow = LhT + (size_t)b * (D / 2) * K + i0;  // uniform base
    float acc[8] = {0.f, 0.f, 0.f, 0.f, 0.f, 0.f, 0.f, 0.f};
    float sr = 0.f;
#pragma unroll 8
    for (int dp = 0; dp < D / 2; ++dp) {
      const unsigned rr = rc[(size_t)dp * K];
      const uint4 lh4a = *(const uint4*)&lrow[(size_t)dp * K];      // s_load
      const uint4 lh4b = *(const uint4*)&lrow[(size_t)dp * K + 4];  // s_load
      const h2v s2 = u2h(ssg[dp]);
      const h2v rv = u2h(rr);
      sr = fdot2f(s2, rv, sr);
      acc[0] = fdot2f(s2, relu2(u2h(lh4a.x) + rv), acc[0]);
      acc[1] = fdot2f(s2, relu2(u2h(lh4a.y) + rv), acc[1]);
      acc[2] = fdot2f(s2, relu2(u2h(lh4a.z) + rv), acc[2]);
      acc[3] = fdot2f(s2, relu2(u2h(lh4a.w) + rv), acc[3]);
      acc[4] = fdot2f(s2, relu2(u2h(lh4b.x) + rv), acc[4]);
      acc[5] = fdot2f(s2, relu2(u2h(lh4b.y) + rv), acc[5]);
      acc[6] = fdot2f(s2, relu2(u2h(lh4b.z) + rv), acc[6]);
      acc[7] = fdot2f(s2, relu2(u2h(lh4b.w) + rv), acc[7]);
    }
#pragma unroll
    for (int ii = 0; ii < TI; ++ii)
      seT[ii][t] = acc[ii] + 0.25f * (sSL[ii] + sr) +
                   bias[(size_t)(i0 + ii) * K + t];
  }
  __syncthreads();

  // ---- D: softmax; wave w owns row w (8 waves); pack to f16 ----
  {
    const int w = t >> 6, lane = t & 63;
    float2 v[4];
    float m = -1e30f;
#pragma unroll
    for (int q = 0; q < 4; ++q) {
      v[q] = *(const float2*)&seT[w][2 * lane + 128 * q];
      m = fmaxf(m, fmaxf(v[q].x, v[q].y));
    }
#pragma unroll
    for (int off = 32; off > 0; off >>= 1) m = fmaxf(m, __shfl_xor(m, off, 64));
    float s = 0.f;
#pragma unroll
    for (int q = 0; q < 4; ++q) {
      v[q].x = __expf(v[q].x - m);
      v[q].y = __expf(v[q].y - m);
      s += v[q].x + v[q].y;
    }
#pragma unroll
    for (int off = 32; off > 0; off >>= 1) s += __shfl_xor(s, off, 64);
    const float inv = 1.f / s;
#pragma unroll
    for (int q = 0; q < 4; ++q)
      sattn16[w][lane + 64 * q] = pkrtz(v[q].x * inv, v[q].y * inv);
  }
  __syncthreads();

  // ---- E: agg; thread = (dg = t>>4 owns 4 d-rows, jr = t&15 owns 32 j's).
  // Two passes over j-chunks keep attn regs at 64 VGPR.
  {
    const int jr = t & 15, dg = t >> 4;
    const unsigned* xh = XhT + (size_t)b * D * (K / 2);
    float accT[4][8];
#pragma unroll
    for (int r = 0; r < 4; ++r)
#pragma unroll
      for (int i = 0; i < 8; ++i) accT[r][i] = 0.f;
#pragma unroll
    for (int p = 0; p < 2; ++p) {
      uint4 ar[8][2];
#pragma unroll
      for (int i = 0; i < 8; ++i)
#pragma unroll
        for (int qq = 0; qq < 2; ++qq)
          ar[i][qq] = *(const uint4*)&sattn16[i][4 * (jr + 16 * (2 * p + qq))];
#pragma unroll
      for (int r = 0; r < 4; ++r) {
        const int d = dg * 4 + r;
#pragma unroll
        for (int qq = 0; qq < 2; ++qq) {
          const uint4 xp =
              *(const uint4*)&xh[(size_t)d * (K / 2) +
                                 4 * (jr + 16 * (2 * p + qq))];
#pragma unroll
          for (int i = 0; i < 8; ++i) {
            accT[r][i] = fdot2f(u2h(ar[i][qq].x), u2h(xp.x), accT[r][i]);
            accT[r][i] = fdot2f(u2h(ar[i][qq].y), u2h(xp.y), accT[r][i]);
            accT[r][i] = fdot2f(u2h(ar[i][qq].z), u2h(xp.z), accT[r][i]);
            accT[r][i] = fdot2f(u2h(ar[i][qq].w), u2h(xp.w), accT[r][i]);
          }
        }
      }
    }
#pragma unroll
    for (int r = 0; r < 4; ++r) {
#pragma unroll
      for (int i = 0; i < 8; ++i) {
        accT[r][i] += __shfl_xor(accT[r][i], 1, 64);
        accT[r][i] += __shfl_xor(accT[r][i], 2, 64);
        accT[r][i] += __shfl_xor(accT[r][i], 4, 64);
        accT[r][i] += __shfl_xor(accT[r][i], 8, 64);
      }
      if (jr == 0) {
        const int d = dg * 4 + r;
        const float* xrow = x + ((size_t)b * D + d) * K + i0;
        const float4 xv0 = *(const float4*)&xrow[0];
        const float4 xv1 = *(const float4*)&xrow[4];
        const float xr[8] = {xv0.x, xv0.y, xv0.z, xv0.w,
                             xv1.x, xv1.y, xv1.z, xv1.w};
        float* orow = out + ((size_t)b * D + d) * K + i0;
#pragma unroll
        for (int i = 0; i < 8; ++i) {
          const float sg = 1.f / (1.f + __expf(-accT[r][i]));
          orow[i] = sg + xr[i];
        }
      }
    }
  }
}

// ---------------- Fallback (ws too small): fused, ws-free ----------------
#define ALPHA 0.2f
__global__ __launch_bounds__(512) void gat_fused(
    const float* __restrict__ x, const float* __restrict__ lin_w,
    const float* __restrict__ lin_b, const float* __restrict__ a,
    const float* __restrict__ bias, float* __restrict__ out) {
  const int i = blockIdx.x, b = blockIdx.y, t = threadIdx.x;
  __shared__ float sxi[D], sLi[D], sa[D];
  __shared__ float lpart[4 * D];
  __shared__ float xtT[D * 64];
  __shared__ float epars[8 * 64];
  __shared__ float se[K];
  __shared__ float sattn[K], spart[K];
  __shared__ float sred[8];

  if (t < D) {
    sxi[t] = x[((size_t)b * D + t) * K + i];
    sa[t] = a[t];
  }
  __syncthreads();
  {
    const int c = t & (D - 1), q = t >> 7;
    float acc = 0.f;
    const float* W1 = lin_w + c;
#pragma unroll 8
    for (int d = q * 32; d < q * 32 + 32; ++d)
      acc = fmaf(sxi[d], W1[(size_t)d * D], acc);
    lpart[q * D + c] = acc;
  }
  __syncthreads();
  if (t < D)
    sLi[t] = lin_b[t] + lpart[t] + lpart[D + t] + lpart[2 * D + t] +
             lpart[3 * D + t];
  __syncthreads();

  for (int jt = 0; jt < K / 64; ++jt) {
    const int j0 = jt * 64;
    for (int idx = t; idx < D * 64; idx += 512)
      xtT[idx] = x[((size_t)b * D + (idx >> 6)) * K + j0 + (idx & 63)];
    __syncthreads();
    const int jj = t & 63, g = t >> 6, dp0 = g * 16;
    float accv[16];
#pragma unroll
    for (int v = 0; v < 16; ++v) accv[v] = 0.f;
    for (int dc = 0; dc < D; dc += 16) {
      float xv[16];
#pragma unroll
      for (int u = 0; u < 16; ++u) xv[u] = xtT[(dc + u) * 64 + jj];
#pragma unroll
      for (int u = 0; u < 16; ++u) {
        const float* W2r = lin_w + (size_t)(D + dc + u) * D + dp0;
#pragma unroll
        for (int v = 0; v < 16; ++v) accv[v] = fmaf(xv[u], W2r[v], accv[v]);
      }
    }
    float ep = 0.f;
#pragma unroll
    for (int v = 0; v < 16; ++v) {
      const float pre = sLi[dp0 + v] + accv[v];
      ep = fmaf(sa[dp0 + v], pre > 0.f ? pre : ALPHA * pre, ep);
    }
    epars[g * 64 + jj] = ep;
    __syncthreads();
    if (t < 64) {
      float esum = bias[(size_t)i * K + j0 + t];
#pragma unroll
      for (int g2 = 0; g2 < 8; ++g2) esum += epars[g2 * 64 + t];
      se[j0 + t] = esum;
    }
    __syncthreads();
  }

  float e = se[t];
  float m = e;
#pragma unroll
  for (int off = 32; off > 0; off >>= 1) m = fmaxf(m, __shfl_xor(m, off, 64));
  if ((t & 63) == 0) sred[t >> 6] = m;
  __syncthreads();
  m = sred[0];
#pragma unroll
  for (int w = 1; w < 8; ++w) m = fmaxf(m, sred[w]);
  const float ev = __expf(e - m);
  float s = ev;
#pragma unroll
  for (int off = 32; off > 0; off >>= 1) s += __shfl_xor(s, off, 64);
  __syncthreads();
  if ((t & 63) == 0) sred[t >> 6] = s;
  __syncthreads();
  s = 0.f;
#pragma unroll
  for (int w = 0; w < 8; ++w) s += sred[w];
  sattn[t] = ev * (1.f / s);
  __syncthreads();

  const int d = t >> 2, c = t & 3;
  const float4* X4 = (const float4*)(x + ((size_t)b * D + d) * K);
  const float4* A4 = (const float4*)sattn;
  float p = 0.f;
#pragma unroll 4
  for (int q = 0; q < K / 16; ++q) {
    const int idx = c + 4 * q;
    float4 xv = X4[idx], av = A4[idx];
    p = fmaf(av.x, xv.x, p);
    p = fmaf(av.y, xv.y, p);
    p = fmaf(av.z, xv.z, p);
    p = fmaf(av.w, xv.w, p);
  }
  spart[t] = p;
  __syncthreads();
  if (t < D) {
    const float agg =
        spart[4 * t] + spart[4 * t + 1] + spart[4 * t + 2] + spart[4 * t + 3];
    const float sg = 1.f / (1.f + __expf(-agg));
    out[((size_t)b * D + t) * K + i] = sg + sxi[t];
  }
}

extern "C" void kernel_launch(void* const* d_in, const int* in_sizes, int n_in,
                              void* d_out, int out_size, void* d_ws,
                              size_t ws_size, hipStream_t stream) {
  const float* x = (const float*)d_in[0];
  const float* lin_w = (const float*)d_in[1];
  const float* lin_b = (const float*)d_in[2];
  const float* a = (const float*)d_in[3];
  const float* bias = (const float*)d_in[4];
  float* out = (float*)d_out;

  const size_t half_words = (size_t)B * (D / 2) * K;  // 512 KB each (L,R)
  const size_t xh_words = (size_t)B * D * (K / 2);    // 512 KB
  const size_t need = (2 * half_words + xh_words) * sizeof(unsigned);
  if (ws_size >= need && d_ws != nullptr) {
    unsigned* LhT = (unsigned*)d_ws;
    unsigned* RhT = LhT + half_words;
    unsigned* XhT = RhT + half_words;
    gat_lr16<<<dim3(K / 64, D / 16, B), 256, 0, stream>>>(x, lin_w, lin_b, a,
                                                          LhT, RhT, XhT);
    gat_attn16<<<dim3(K / TI, B), 512, 0, stream>>>(x, a, bias, LhT, RhT, XhT,
                                                    out);
  } else {
    gat_fused<<<dim3(K, B), 512, 0, stream>>>(x, lin_w, lin_b, a, bias, out);
  }
}